// Round 17
// baseline (544.548 us; speedup 1.0000x reference)
//
#include <hip/hip_runtime.h>

// ============================================================================
// GLM4-MoE attention layer on MI355X (gfx950), fp16 MFMA pipeline.
// Round 17: GEMM2 rebuilt for the extended-VGPR regime. Pipe arithmetic:
// wave 128x64 -> LDS 750cy vs MFMA 310cy/SIMD = 41% ceiling (observed 38%).
// New GEMM2: 4 waves (256 thr, launch_bounds(256,1) -> up to 512 VGPR/wave),
// wave-tile 128x128 (acc 256 VGPR), tile 256x256, LDS 128KB dbuf unchanged.
// LDS 500cy vs MFMA 620cy/SIMD -> MFMA-bound. Staging: 32-row ST groups,
// 16 loads/wave/tile; ledger: ph0 stages A-hi(t+1)->buf^1 (4), ph3 stages
// B(t+2)+A-lo(t+2)->buf (12); vmcnt(12) steady retires exactly t+1,
// t=62 -> vmcnt(0). GEMM1 (r16 256x384), attn (r13), prep (r14) unchanged.
// ============================================================================

typedef _Float16 f16;
typedef _Float16 f16x8 __attribute__((ext_vector_type(8)));
typedef float f32x4 __attribute__((ext_vector_type(4)));
typedef float f32x16 __attribute__((ext_vector_type(16)));

static constexpr int Bn = 2, Sn = 2048, Hn = 4096, NH = 32, NKV = 8, HD = 128;
static constexpr float QSC = 0.08838834764831845f * 1.44269504088896340736f; // 1/sqrt(128)*log2e

#define AS1 __attribute__((address_space(1)))
#define AS3 __attribute__((address_space(3)))

__device__ __forceinline__ void async_ld16(const void* g, void* l) {
    __builtin_amdgcn_global_load_lds((const AS1 void*)g, (AS3 void*)l, 16, 0, 0);
}

__device__ __forceinline__ unsigned pk2(float a, float b) {
    unsigned r;
    asm("v_cvt_pkrtz_f16_f32 %0, %1, %2" : "=v"(r) : "v"(a), "v"(b));
    return r;
}

// native exp2: v_exp_f32 computes 2^x
__device__ __forceinline__ float fexp2(float x) {
    float r;
    asm("v_exp_f32 %0, %1" : "=v"(r) : "v"(x));
    return r;
}

// ---------------------------------------------------------------------------
// Merged prep: blocks [0,8192) = hidden f32->f16 convert (8 elems/thread);
// blocks [8192,18432) = four 64x64 transpose-converts (wq/wk/wv/wo).
__global__ __launch_bounds__(256) void k_prep(
    const float* __restrict__ hs, f16* __restrict__ hid,
    const float* __restrict__ wq, const float* __restrict__ wk,
    const float* __restrict__ wv, const float* __restrict__ wo,
    f16* __restrict__ wqkv_t, f16* __restrict__ wo_t) {
    int bid = blockIdx.x;
    if (bid < 8192) {
        long i = ((long)bid * 256 + threadIdx.x) * 8;
        float4 a = *(const float4*)(hs + i);
        float4 b = *(const float4*)(hs + i + 4);
        f16x8 o = {(f16)a.x, (f16)a.y, (f16)a.z, (f16)a.w,
                   (f16)b.x, (f16)b.y, (f16)b.z, (f16)b.w};
        *(f16x8*)(hid + i) = o;
        return;
    }
    bid -= 8192;
    const float* src;
    f16* dst;
    int N, bx, by;
    if (bid < 4096)      { src = wq; dst = wqkv_t;                    N = 4096; bx = bid & 63; by = bid >> 6; }
    else if (bid < 5120) { bid -= 4096; src = wk; dst = wqkv_t + (long)4096 * 4096; N = 1024; bx = bid & 15; by = bid >> 4; }
    else if (bid < 6144) { bid -= 5120; src = wv; dst = wqkv_t + (long)5120 * 4096; N = 1024; bx = bid & 15; by = bid >> 4; }
    else                 { bid -= 6144; src = wo; dst = wo_t;         N = 4096; bx = bid & 63; by = bid >> 6; }
    __shared__ float tile[64][65];
    const int k0 = by * 64, n0 = bx * 64;
    const int tx = threadIdx.x & 63, ty = threadIdx.x >> 6;   // (64,4)
#pragma unroll
    for (int r = ty; r < 64; r += 4)
        tile[r][tx] = src[(long)(k0 + r) * N + (n0 + tx)];
    __syncthreads();
#pragma unroll
    for (int r = ty; r < 64; r += 4)
        dst[(long)(n0 + r) * 4096 + (k0 + tx)] = (f16)tile[tx][r];
}

// ---------------------------------------------------------------------------
// 256x384 GEMM core (r16-proven): 8 waves (2M x 4N), wave 128x96, BK=64.
// LDS 160KB: buf c at c*81920; A [256r][128B] at +0; B [384r] at +32768.
__device__ __forceinline__ void gemm384_core(
    const f16* __restrict__ A, const f16* __restrict__ Bt,
    char* L, int m0, int n0, f32x4 acc[8][6]) {
    const int t = threadIdx.x, lane = t & 63, wave = t >> 6;
    const int wm = wave >> 2, wn = wave & 3;
    const int fr = lane & 15, fg = lane >> 4;

    const int srowL = wave * 8 + (lane >> 3);
    const int scol  = 8 * ((lane & 7) ^ (lane >> 3));
    const f16* ga = A  + (long)(m0 + srowL) * 4096 + scol;
    const f16* gb = Bt + (long)(n0 + srowL) * 4096 + scol;
    const int woff = wave * 1024;

    auto ST = [&](int sel, int c, int row0, int kt) {
        const f16* g = sel ? gb : ga;
        async_ld16(g + (long)row0 * 4096 + kt * 64,
                   L + c * 81920 + sel * 32768 + row0 * 128 + woff);
    };

    ST(0, 0, 0, 0); ST(0, 0, 64, 0); ST(0, 0, 128, 0); ST(0, 0, 192, 0);
#pragma unroll
    for (int r = 0; r < 384; r += 64) ST(1, 0, r, 0);
#pragma unroll
    for (int r = 0; r < 384; r += 64) ST(1, 1, r, 1);
    ST(0, 1, 0, 1); ST(0, 1, 128, 1);
    asm volatile("s_waitcnt vmcnt(8)" ::: "memory");
    __builtin_amdgcn_s_barrier();

    const int abase = wm * 128;
    const int bbase = wn * 96;

    for (int tt = 0; tt < 64; ++tt) {
        const int c = tt & 1;
        const char* bufA = L + c * 81920;
        const char* bufB = bufA + 32768;
        f16x8 bf[6];

#pragma unroll
        for (int ph = 0; ph < 4; ++ph) {
            const int ks = ph >> 1, mh = ph & 1;
            if (mh == 0) {
#pragma unroll
                for (int nf = 0; nf < 6; ++nf) {
                    int r = bbase + nf * 16 + fr;
                    bf[nf] = *(const f16x8*)(bufB + r * 128 +
                                 ((ks * 64 + 16 * fg) ^ ((r & 7) << 4)));
                }
            }
            f16x8 af[4];
#pragma unroll
            for (int i = 0; i < 4; ++i) {
                int r = abase + mh * 64 + i * 16 + fr;
                af[i] = *(const f16x8*)(bufA + r * 128 +
                             ((ks * 64 + 16 * fg) ^ ((r & 7) << 4)));
            }
            if (ph == 0) { if (tt + 1 < 64) { ST(0, c ^ 1,  64, tt + 1);
                                              ST(0, c ^ 1, 192, tt + 1); } }
            if (ph == 3) { if (tt + 2 < 64) {
#pragma unroll
                for (int r = 0; r < 384; r += 64) ST(1, c, r, tt + 2);
                ST(0, c, 0, tt + 2); ST(0, c, 128, tt + 2); } }
            __builtin_amdgcn_s_barrier();
            __builtin_amdgcn_s_setprio(1);
#pragma unroll
            for (int i = 0; i < 4; ++i)
#pragma unroll
                for (int nf = 0; nf < 6; ++nf)
                    acc[mh * 4 + i][nf] = __builtin_amdgcn_mfma_f32_16x16x32_f16(
                        af[i], bf[nf], acc[mh * 4 + i][nf], 0, 0, 0);
            __builtin_amdgcn_s_setprio(0);
            if (ph == 3) {
                if (tt < 62)       asm volatile("s_waitcnt vmcnt(8)" ::: "memory");
                else if (tt == 62) asm volatile("s_waitcnt vmcnt(0)" ::: "memory");
            }
            __builtin_amdgcn_s_barrier();
        }
    }
}

// ---------------------------------------------------------------------------
// GEMM2 core: 4 waves (2M x 2N), wave-tile 128x128, tile 256x256, BK=64.
// Extended VGPR regime: acc 8x8xf32x4 = 256 VGPR, 1 wave/SIMD.
// LDS 128KB: buf c at c*65536; A [256r][128B] at +0; B at +32768; swizzled.
// Staging: ST = 32-row group (1 instr/wave, 4 waves cover 32 rows).
// 16 loads/wave/tile; ph0 stages A-hi(t+1) (4), ph3 stages B+A-lo(t+2) (12);
// vmcnt(12) steady (retires exactly tile t+1), t==62 -> vmcnt(0).
__device__ __forceinline__ void gemm2_core(
    const f16* __restrict__ A, const f16* __restrict__ Bt,
    char* L, int m0, int n0, f32x4 acc[8][8]) {
    const int t = threadIdx.x, lane = t & 63, wave = t >> 6;   // 4 waves
    const int wm = wave >> 1, wn = wave & 1;
    const int fr = lane & 15, fg = lane >> 4;

    const int srowL = wave * 8 + (lane >> 3);
    const int scol  = 8 * ((lane & 7) ^ (lane >> 3));
    const f16* ga = A  + (long)(m0 + srowL) * 4096 + scol;
    const f16* gb = Bt + (long)(n0 + srowL) * 4096 + scol;
    const int woff = wave * 1024;

    auto ST = [&](int sel, int c, int row0, int kt) {   // 32 rows
        const f16* g = sel ? gb : ga;
        async_ld16(g + (long)row0 * 4096 + kt * 64,
                   L + c * 65536 + sel * 32768 + row0 * 128 + woff);
    };
    auto ST64 = [&](int sel, int c, int row0, int kt) {
        ST(sel, c, row0, kt); ST(sel, c, row0 + 32, kt);
    };

    // prologue: t0 full (16), t1 B-all + A-lo (12)
    ST64(0, 0, 0, 0); ST64(0, 0, 64, 0); ST64(0, 0, 128, 0); ST64(0, 0, 192, 0);
    ST64(1, 0, 0, 0); ST64(1, 0, 64, 0); ST64(1, 0, 128, 0); ST64(1, 0, 192, 0);
    ST64(1, 1, 0, 1); ST64(1, 1, 64, 1); ST64(1, 1, 128, 1); ST64(1, 1, 192, 1);
    ST64(0, 1, 0, 1); ST64(0, 1, 128, 1);
    asm volatile("s_waitcnt vmcnt(12)" ::: "memory");  // t0 landed; t1's 12 fly
    __builtin_amdgcn_s_barrier();

    const int abase = wm * 128;
    const int bbase = wn * 128;

    for (int tt = 0; tt < 64; ++tt) {
        const int c = tt & 1;
        const char* bufA = L + c * 65536;
        const char* bufB = bufA + 32768;
        f16x8 bf[8];

#pragma unroll
        for (int ph = 0; ph < 4; ++ph) {
            const int ks = ph >> 1, mh = ph & 1;
            if (mh == 0) {
#pragma unroll
                for (int nf = 0; nf < 8; ++nf) {
                    int r = bbase + nf * 16 + fr;
                    bf[nf] = *(const f16x8*)(bufB + r * 128 +
                                 ((ks * 64 + 16 * fg) ^ ((r & 7) << 4)));
                }
            }
            f16x8 af[4];
#pragma unroll
            for (int i = 0; i < 4; ++i) {
                int r = abase + mh * 64 + i * 16 + fr;
                af[i] = *(const f16x8*)(bufA + r * 128 +
                             ((ks * 64 + 16 * fg) ^ ((r & 7) << 4)));
            }
            if (ph == 0) { if (tt + 1 < 64) { ST64(0, c ^ 1,  64, tt + 1);
                                              ST64(0, c ^ 1, 192, tt + 1); } }
            if (ph == 3) { if (tt + 2 < 64) {
                ST64(1, c, 0, tt + 2); ST64(1, c, 64, tt + 2);
                ST64(1, c, 128, tt + 2); ST64(1, c, 192, tt + 2);
                ST64(0, c, 0, tt + 2); ST64(0, c, 128, tt + 2); } }
            __builtin_amdgcn_s_barrier();
            __builtin_amdgcn_s_setprio(1);
#pragma unroll
            for (int i = 0; i < 4; ++i)
#pragma unroll
                for (int nf = 0; nf < 8; ++nf)
                    acc[mh * 4 + i][nf] = __builtin_amdgcn_mfma_f32_16x16x32_f16(
                        af[i], bf[nf], acc[mh * 4 + i][nf], 0, 0, 0);
            __builtin_amdgcn_s_setprio(0);
            if (ph == 3) {
                if (tt < 62)       asm volatile("s_waitcnt vmcnt(12)" ::: "memory");
                else if (tt == 62) asm volatile("s_waitcnt vmcnt(0)" ::: "memory");
            }
            __builtin_amdgcn_s_barrier();
        }
    }
}

// GEMM1: hidden @ Wqkv^T -> q (RoPE+scale fused), k (RoPE fused), V^T (fused).
// 256x384 tiles -> 256 blocks = 1 full dispatch round.
__global__ __launch_bounds__(512) void k_gemm_qkv(
    const f16* __restrict__ A, const f16* __restrict__ Bt,
    f16* __restrict__ q, f16* __restrict__ kk_, f16* __restrict__ vt,
    const float* __restrict__ cosb, const float* __restrict__ sinb) {
    __shared__ __align__(16) char L[163840];       // full 160KB pool
    const int bid = blockIdx.x;                    // 256 = 16m x 16n
    const int swzb = (bid & 7) * 32 + (bid >> 3);  // XCD-bijective
    const int m0 = (swzb >> 4) * 256, n0 = (swzb & 15) * 384;
    f32x4 acc[8][6] = {};
    gemm384_core(A, Bt, L, m0, n0, acc);

    const int lane = threadIdx.x & 63, wave = threadIdx.x >> 6;
    const int wm = wave >> 2, wn = wave & 3;
    const int fr = lane & 15, fg = lane >> 4;
#pragma unroll
    for (int mf = 0; mf < 8; ++mf) {
        int r0 = m0 + wm * 128 + mf * 16 + 4 * fg;
        int b = r0 >> 11, s = r0 & (Sn - 1);   // r0 multiple of 4: same b, s..s+3
        const float* cb_ = cosb + ((long)b * Sn + s) * 64;
        const float* sb_ = sinb + ((long)b * Sn + s) * 64;
#pragma unroll
        for (int nf = 0; nf < 6; ++nf) {
            int cc = n0 + wn * 96 + nf * 16 + fr;
            int d = cc & 127;
            if (cc < 5120) {
                float vals[4];
#pragma unroll
                for (int e = 0; e < 4; ++e) vals[e] = acc[mf][nf][e];
                if (d < 64) {
                    int ci = d >> 1;
                    bool odd = (d & 1);
#pragma unroll
                    for (int e = 0; e < 4; ++e) {
                        float p = __shfl_xor(vals[e], 1, 64);   // lane^1 = d^1
                        float c = cb_[e * 64 + ci], sv = sb_[e * 64 + ci];
                        vals[e] = odd ? (vals[e] * c + p * sv)
                                      : (vals[e] * c - p * sv);
                    }
                }
                if (cc < 4096) {
                    int h = cc >> 7;
#pragma unroll
                    for (int e = 0; e < 4; ++e)
                        q[(((long)b * NH + h) * Sn + s + e) * HD + d] =
                            (f16)(vals[e] * QSC);
                } else {
                    int h = (cc - 4096) >> 7;
#pragma unroll
                    for (int e = 0; e < 4; ++e)
                        kk_[(((long)b * NKV + h) * Sn + s + e) * HD + d] =
                            (f16)vals[e];
                }
            } else {
                int h = (cc - 5120) >> 7;
                uint2 w = {pk2(acc[mf][nf][0], acc[mf][nf][1]),
                           pk2(acc[mf][nf][2], acc[mf][nf][3])};
                *(uint2*)&vt[(((long)b * NKV + h) * HD + d) * Sn + s] = w;
            }
        }
    }
}

// GEMM2: attn_out @ wo^T -> d_out f32, 256 blocks (16x16), 4 waves/block,
// extended VGPR (launch_bounds(256,1) -> up to 512 VGPR/wave).
__global__ __launch_bounds__(256, 1) void k_gemm_out(
    const f16* __restrict__ A, const f16* __restrict__ Bt,
    float* __restrict__ out) {
    __shared__ __align__(16) char L[131072];
    const int bid = blockIdx.x;
    const int swzb = (bid & 7) * 32 + (bid >> 3);
    const int m0 = (swzb >> 4) * 256, n0 = (swzb & 15) * 256;
    f32x4 acc[8][8] = {};
    gemm2_core(A, Bt, L, m0, n0, acc);

    const int lane = threadIdx.x & 63, wave = threadIdx.x >> 6;
    const int wm = wave >> 1, wn = wave & 1;
    const int fr = lane & 15, fg = lane >> 4;
#pragma unroll
    for (int mf = 0; mf < 8; ++mf) {
        int r0 = m0 + wm * 128 + mf * 16 + 4 * fg;
#pragma unroll
        for (int nf = 0; nf < 8; ++nf) {
            int cc = n0 + wn * 128 + nf * 16 + fr;
#pragma unroll
            for (int e = 0; e < 4; ++e)
                out[(long)(r0 + e) * 4096 + cc] = acc[mf][nf][e];
        }
    }
}

// ---------------------------------------------------------------------------
// Flash attention v6 (r13-proven): QBLK=256 (8 waves x 32 q), 32x32x16 MFMA,
// in-register P via pk2 + shfl_xor(32); swapped QK^T (q lane-local softmax).
//   A: row=lane&31, k=8*(lane>>5)+e   B: k=8*(lane>>5)+e, col=lane&31
//   C: col=lane&31, row=(reg&3)+8*(reg>>2)+4*(lane>>5)

__device__ __forceinline__ f16x8 ld_sw256(const f16* base, int r, int c) {
    int byte = r * 256 + ((c * 2) ^ ((r & 7) << 4));
    return *(const f16x8*)((const char*)base + byte);
}
__device__ __forceinline__ f16x8 ld_sw128(const f16* base, int r, int c) {
    int byte = r * 128 + ((c * 2) ^ ((r & 7) << 4));
    return *(const f16x8*)((const char*)base + byte);
}

// K tile [64 kv][128 d] f16 = 16KB = 16 chunks; 8 waves x 2 chunks
__device__ __forceinline__ void stage_k(const f16* __restrict__ Kb, f16* ksm,
                                        int k0, int wave, int lane) {
#pragma unroll
    for (int i = 0; i < 2; ++i) {
        int dbase = (i * 8 + wave) * 1024;
        int d = dbase + lane * 16;
        int row = d >> 8;
        int cb = (d & 255) ^ ((row & 7) << 4);
        async_ld16(Kb + (long)(k0 + row) * HD + (cb >> 1), (char*)ksm + dbase);
    }
}
__device__ __forceinline__ void stage_v(const f16* __restrict__ Vb, f16* vsm,
                                        int k0, int wave, int lane) {
#pragma unroll
    for (int i = 0; i < 2; ++i) {
        int dbase = (i * 8 + wave) * 1024;
        int d = dbase + lane * 16;
        int row = d >> 7;
        int cb = (d & 127) ^ ((row & 7) << 4);
        async_ld16(Vb + (long)row * Sn + k0 + (cb >> 1), (char*)vsm + dbase);
    }
}

__global__ __launch_bounds__(512) void k_attn(
    const f16* __restrict__ Q, const f16* __restrict__ K,
    const f16* __restrict__ Vt, f16* __restrict__ O) {
    __shared__ __align__(16) f16 Ksm[2][64 * 128];   // 32KB
    __shared__ __align__(16) f16 Vsm[2][128 * 64];   // 32KB

    // grid 512: id = ((b*4 + hg)*8 + pos)*8 + kvh; pos pairs (heavy, light)
    const int id = blockIdx.x;
    const int kvh = id & 7;                 // XCD-local KV
    const int r_ = id >> 3;
    const int pos = r_ & 7;
    const int qt = (pos & 1) ? (pos >> 1) : (7 - (pos >> 1)); // 7,0,6,1,5,2,4,3
    const int hg = (r_ >> 3) & 3;
    const int b  = r_ >> 5;
    const int h  = kvh * 4 + hg;
    const int q0 = qt * 256;
    const int t = threadIdx.x, lane = t & 63, wave = t >> 6;
    const int q0w = q0 + wave * 32;
    const int lq = lane & 31, hi = lane >> 5;

    const f16* Qb = Q + ((long)(b * NH + h) * Sn) * HD;
    const f16* Kb = K + ((long)(b * NKV + kvh) * Sn) * HD;
    const f16* Vb = Vt + ((long)(b * NKV + kvh) * HD) * Sn;

    f16x8 qf[8];
#pragma unroll
    for (int s = 0; s < 8; ++s)
        qf[s] = *(const f16x8*)&Qb[(long)(q0w + lq) * HD + 16 * s + 8 * hi];

    f32x16 oacc[4] = {};
    float mrun = -1e30f, lrun = 0.f;

    const int nt = q0 / 64 + 4;   // cover q0+255
    stage_k(Kb, Ksm[0], 0, wave, lane);
    stage_v(Vb, Vsm[0], 0, wave, lane);

    for (int kt = 0; kt < nt; ++kt) {
        const int k0 = kt * 64;
        const int cur = kt & 1;
        if (kt + 1 < nt) {
            stage_k(Kb, Ksm[cur ^ 1], (kt + 1) * 64, wave, lane);
            stage_v(Vb, Vsm[cur ^ 1], (kt + 1) * 64, wave, lane);
            asm volatile("s_waitcnt vmcnt(4)" ::: "memory"); // cur tile landed
        } else {
            asm volatile("s_waitcnt vmcnt(0)" ::: "memory");
        }
        __builtin_amdgcn_s_barrier();

        if (k0 <= q0w + 31) {
            f32x16 st[2] = {};
#pragma unroll
            for (int s = 0; s < 8; ++s) {
                f16x8 kf0 = ld_sw256(Ksm[cur], lq,      16 * s + 8 * hi);
                f16x8 kf1 = ld_sw256(Ksm[cur], 32 + lq, 16 * s + 8 * hi);
                st[0] = __builtin_amdgcn_mfma_f32_32x32x16_f16(kf0, qf[s], st[0], 0, 0, 0);
                st[1] = __builtin_amdgcn_mfma_f32_32x32x16_f16(kf1, qf[s], st[1], 0, 0, 0);
            }
            const bool full = (k0 + 63 <= q0w);
            if (!full) {
#pragma unroll
                for (int mt = 0; mt < 2; ++mt)
#pragma unroll
                    for (int r = 0; r < 16; ++r) {
                        int kvv = k0 + 32 * mt + (r & 3) + 8 * (r >> 2) + 4 * hi;
                        if (kvv > q0w + lq) st[mt][r] = -1e30f;
                    }
            }
            float pm = st[0][0];
#pragma unroll
            for (int r = 1; r < 16; ++r) pm = fmaxf(pm, st[0][r]);
#pragma unroll
            for (int r = 0; r < 16; ++r) pm = fmaxf(pm, st[1][r]);
            pm = fmaxf(pm, __shfl_xor(pm, 32, 64));
            if (__any(pm > mrun + 8.f)) {
                float mn = fmaxf(mrun, pm);
                float sc = fexp2(mrun - mn);
                mrun = mn;
                lrun *= sc;
                float scr[16];
#pragma unroll
                for (int r = 0; r < 16; ++r)
                    scr[r] = __shfl(sc, (r & 3) + 8 * (r >> 2) + 4 * hi, 64);
#pragma unroll
                for (int db = 0; db < 4; ++db)
#pragma unroll
                    for (int r = 0; r < 16; ++r)
                        oacc[db][r] *= scr[r];
            }
            unsigned pw[2][8];
#pragma unroll
            for (int mt = 0; mt < 2; ++mt)
#pragma unroll
                for (int i = 0; i < 8; ++i) {
                    float p0 = fexp2(st[mt][2 * i]     - mrun);
                    float p1 = fexp2(st[mt][2 * i + 1] - mrun);
                    lrun += p0 + p1;
                    pw[mt][i] = pk2(p0, p1);
                }
#pragma unroll
            for (int s = 0; s < 4; ++s) {
                const int mt = s >> 1, sl = s & 1;
                unsigned a0 = pw[mt][4 * sl], a1 = pw[mt][4 * sl + 1];
                unsigned a2 = pw[mt][4 * sl + 2], a3 = pw[mt][4 * sl + 3];
                unsigned own0 = hi ? a2 : a0, own1 = hi ? a3 : a1;
                unsigned snd0 = hi ? a0 : a2, snd1 = hi ? a1 : a3;
                unsigned rx0 = (unsigned)__shfl_xor((int)snd0, 32, 64);
                unsigned rx1 = (unsigned)__shfl_xor((int)snd1, 32, 64);
                union { unsigned u[4]; f16x8 v; } pu;
                pu.u[0] = hi ? rx0 : own0;
                pu.u[1] = hi ? rx1 : own1;
                pu.u[2] = hi ? own0 : rx0;
                pu.u[3] = hi ? own1 : rx1;
#pragma unroll
                for (int db = 0; db < 4; ++db) {
                    f16x8 vf = ld_sw128(Vsm[cur], 32 * db + lq, 16 * s + 8 * hi);
                    oacc[db] = __builtin_amdgcn_mfma_f32_32x32x16_f16(pu.v, vf, oacc[db], 0, 0, 0);
                }
            }
        }
        __builtin_amdgcn_s_barrier();
    }

    lrun += __shfl_xor(lrun, 32, 64);
    float li = 1.f / lrun;
    float ir[16];
#pragma unroll
    for (int r = 0; r < 16; ++r)
        ir[r] = __shfl(li, (r & 3) + 8 * (r >> 2) + 4 * hi, 64);
#pragma unroll
    for (int db = 0; db < 4; ++db)
#pragma unroll
        for (int r = 0; r < 16; ++r) {
            int qloc = (r & 3) + 8 * (r >> 2) + 4 * hi;
            long tok = (long)b * Sn + q0w + qloc;
            O[tok * (NH * HD) + h * HD + 32 * db + lq] = (f16)(oacc[db][r] * ir[r]);
        }
}

// sentinel if workspace too small
__global__ void k_ws_fail(float* out) { out[0] = 1.0e9f; }

// ---------------------------------------------------------------------------
extern "C" void kernel_launch(void* const* d_in, const int* in_sizes, int n_in,
                              void* d_out, int out_size, void* d_ws, size_t ws_size,
                              hipStream_t stream) {
    const float* hs   = (const float*)d_in[0];
    const float* wq   = (const float*)d_in[1];
    const float* wk   = (const float*)d_in[2];
    const float* wv   = (const float*)d_in[3];
    const float* wo   = (const float*)d_in[4];
    const float* cosb = (const float*)d_in[5];
    const float* sinb = (const float*)d_in[6];
    float* out = (float*)d_out;

    const size_t OFF_WQKV = 0;
    const size_t OFF_WO   = 50331648;
    const size_t OFF_HID  = 83886080;
    const size_t OFF_Q    = 117440512;
    const size_t OFF_K    = 150994944;
    const size_t OFF_VT   = 167772160;
    const size_t WS_NEED  = 176160768;
    if (ws_size < WS_NEED) { k_ws_fail<<<1, 1, 0, stream>>>(out); return; }

    char* ws = (char*)d_ws;
    f16* wqkv_t = (f16*)(ws + OFF_WQKV);
    f16* wo_t   = (f16*)(ws + OFF_WO);
    f16* hid    = (f16*)(ws + OFF_HID);
    f16* qb     = (f16*)(ws + OFF_Q);
    f16* kb     = (f16*)(ws + OFF_K);
    f16* vtb    = (f16*)(ws + OFF_VT);

    // 1 prep dispatch: 8192 cvt blocks + (4096+1024+1024+4096) tcvt blocks
    k_prep<<<dim3(18432), 256, 0, stream>>>(hs, hid, wq, wk, wv, wo, wqkv_t, wo_t);
    k_gemm_qkv<<<dim3(256), 512, 0, stream>>>(hid, wqkv_t, qb, kb, vtb, cosb, sinb);
    k_attn<<<dim3(512), 512, 0, stream>>>(qb, kb, vtb, hid);
    k_gemm_out<<<dim3(256), 256, 0, stream>>>(hid, wo_t, out);
}

// Round 18
// 522.319 us; speedup vs baseline: 1.0426x; 1.0426x over previous
//
#include <hip/hip_runtime.h>

// ============================================================================
// GLM4-MoE attention layer on MI355X (gfx950), fp16 MFMA pipeline.
// Round 18: REVERT of r17's GEMM2 extended-VGPR experiment (regressed +22us:
// 1 wave/SIMD has no latency hiding / possible acc spill). This file is the
// r16 configuration (best measured: 522us):
//   k_prep (merged cvt+4 tcvt) -> k_gemm_qkv (256x384, 160KB LDS, RoPE+V^T
//   fused, 1 full round) -> k_attn (QBLK=256, 32x32 MFMA, in-reg P) ->
//   k_gemm_out (256x256, 8 waves, r15 template).
// ============================================================================

typedef _Float16 f16;
typedef _Float16 f16x8 __attribute__((ext_vector_type(8)));
typedef float f32x4 __attribute__((ext_vector_type(4)));
typedef float f32x16 __attribute__((ext_vector_type(16)));

static constexpr int Bn = 2, Sn = 2048, Hn = 4096, NH = 32, NKV = 8, HD = 128;
static constexpr float QSC = 0.08838834764831845f * 1.44269504088896340736f; // 1/sqrt(128)*log2e

#define AS1 __attribute__((address_space(1)))
#define AS3 __attribute__((address_space(3)))

__device__ __forceinline__ void async_ld16(const void* g, void* l) {
    __builtin_amdgcn_global_load_lds((const AS1 void*)g, (AS3 void*)l, 16, 0, 0);
}

__device__ __forceinline__ unsigned pk2(float a, float b) {
    unsigned r;
    asm("v_cvt_pkrtz_f16_f32 %0, %1, %2" : "=v"(r) : "v"(a), "v"(b));
    return r;
}

// native exp2: v_exp_f32 computes 2^x
__device__ __forceinline__ float fexp2(float x) {
    float r;
    asm("v_exp_f32 %0, %1" : "=v"(r) : "v"(x));
    return r;
}

// ---------------------------------------------------------------------------
// Merged prep: blocks [0,8192) = hidden f32->f16 convert (8 elems/thread);
// blocks [8192,18432) = four 64x64 transpose-converts (wq/wk/wv/wo).
__global__ __launch_bounds__(256) void k_prep(
    const float* __restrict__ hs, f16* __restrict__ hid,
    const float* __restrict__ wq, const float* __restrict__ wk,
    const float* __restrict__ wv, const float* __restrict__ wo,
    f16* __restrict__ wqkv_t, f16* __restrict__ wo_t) {
    int bid = blockIdx.x;
    if (bid < 8192) {
        long i = ((long)bid * 256 + threadIdx.x) * 8;
        float4 a = *(const float4*)(hs + i);
        float4 b = *(const float4*)(hs + i + 4);
        f16x8 o = {(f16)a.x, (f16)a.y, (f16)a.z, (f16)a.w,
                   (f16)b.x, (f16)b.y, (f16)b.z, (f16)b.w};
        *(f16x8*)(hid + i) = o;
        return;
    }
    bid -= 8192;
    const float* src;
    f16* dst;
    int N, bx, by;
    if (bid < 4096)      { src = wq; dst = wqkv_t;                    N = 4096; bx = bid & 63; by = bid >> 6; }
    else if (bid < 5120) { bid -= 4096; src = wk; dst = wqkv_t + (long)4096 * 4096; N = 1024; bx = bid & 15; by = bid >> 4; }
    else if (bid < 6144) { bid -= 5120; src = wv; dst = wqkv_t + (long)5120 * 4096; N = 1024; bx = bid & 15; by = bid >> 4; }
    else                 { bid -= 6144; src = wo; dst = wo_t;         N = 4096; bx = bid & 63; by = bid >> 6; }
    __shared__ float tile[64][65];
    const int k0 = by * 64, n0 = bx * 64;
    const int tx = threadIdx.x & 63, ty = threadIdx.x >> 6;   // (64,4)
#pragma unroll
    for (int r = ty; r < 64; r += 4)
        tile[r][tx] = src[(long)(k0 + r) * N + (n0 + tx)];
    __syncthreads();
#pragma unroll
    for (int r = ty; r < 64; r += 4)
        dst[(long)(n0 + r) * 4096 + (k0 + tx)] = (f16)tile[tx][r];
}

// ---------------------------------------------------------------------------
// 256x384 GEMM core (r16-proven): 8 waves (2M x 4N), wave 128x96, BK=64.
// LDS 160KB: buf c at c*81920; A [256r][128B] at +0; B [384r] at +32768.
__device__ __forceinline__ void gemm384_core(
    const f16* __restrict__ A, const f16* __restrict__ Bt,
    char* L, int m0, int n0, f32x4 acc[8][6]) {
    const int t = threadIdx.x, lane = t & 63, wave = t >> 6;
    const int wm = wave >> 2, wn = wave & 3;
    const int fr = lane & 15, fg = lane >> 4;

    const int srowL = wave * 8 + (lane >> 3);
    const int scol  = 8 * ((lane & 7) ^ (lane >> 3));
    const f16* ga = A  + (long)(m0 + srowL) * 4096 + scol;
    const f16* gb = Bt + (long)(n0 + srowL) * 4096 + scol;
    const int woff = wave * 1024;

    auto ST = [&](int sel, int c, int row0, int kt) {
        const f16* g = sel ? gb : ga;
        async_ld16(g + (long)row0 * 4096 + kt * 64,
                   L + c * 81920 + sel * 32768 + row0 * 128 + woff);
    };

    ST(0, 0, 0, 0); ST(0, 0, 64, 0); ST(0, 0, 128, 0); ST(0, 0, 192, 0);
#pragma unroll
    for (int r = 0; r < 384; r += 64) ST(1, 0, r, 0);
#pragma unroll
    for (int r = 0; r < 384; r += 64) ST(1, 1, r, 1);
    ST(0, 1, 0, 1); ST(0, 1, 128, 1);
    asm volatile("s_waitcnt vmcnt(8)" ::: "memory");
    __builtin_amdgcn_s_barrier();

    const int abase = wm * 128;
    const int bbase = wn * 96;

    for (int tt = 0; tt < 64; ++tt) {
        const int c = tt & 1;
        const char* bufA = L + c * 81920;
        const char* bufB = bufA + 32768;
        f16x8 bf[6];

#pragma unroll
        for (int ph = 0; ph < 4; ++ph) {
            const int ks = ph >> 1, mh = ph & 1;
            if (mh == 0) {
#pragma unroll
                for (int nf = 0; nf < 6; ++nf) {
                    int r = bbase + nf * 16 + fr;
                    bf[nf] = *(const f16x8*)(bufB + r * 128 +
                                 ((ks * 64 + 16 * fg) ^ ((r & 7) << 4)));
                }
            }
            f16x8 af[4];
#pragma unroll
            for (int i = 0; i < 4; ++i) {
                int r = abase + mh * 64 + i * 16 + fr;
                af[i] = *(const f16x8*)(bufA + r * 128 +
                             ((ks * 64 + 16 * fg) ^ ((r & 7) << 4)));
            }
            if (ph == 0) { if (tt + 1 < 64) { ST(0, c ^ 1,  64, tt + 1);
                                              ST(0, c ^ 1, 192, tt + 1); } }
            if (ph == 3) { if (tt + 2 < 64) {
#pragma unroll
                for (int r = 0; r < 384; r += 64) ST(1, c, r, tt + 2);
                ST(0, c, 0, tt + 2); ST(0, c, 128, tt + 2); } }
            __builtin_amdgcn_s_barrier();
            __builtin_amdgcn_s_setprio(1);
#pragma unroll
            for (int i = 0; i < 4; ++i)
#pragma unroll
                for (int nf = 0; nf < 6; ++nf)
                    acc[mh * 4 + i][nf] = __builtin_amdgcn_mfma_f32_16x16x32_f16(
                        af[i], bf[nf], acc[mh * 4 + i][nf], 0, 0, 0);
            __builtin_amdgcn_s_setprio(0);
            if (ph == 3) {
                if (tt < 62)       asm volatile("s_waitcnt vmcnt(8)" ::: "memory");
                else if (tt == 62) asm volatile("s_waitcnt vmcnt(0)" ::: "memory");
            }
            __builtin_amdgcn_s_barrier();
        }
    }
}

// ---------------------------------------------------------------------------
// 256x256 GEMM core (r11/r15-proven) for GEMM2: 8 waves (2M x 4N), BK=64.
__device__ __forceinline__ void gemm256_core(
    const f16* __restrict__ A, const f16* __restrict__ Bt,
    char* L, int m0, int n0, f32x4 acc[8][4]) {
    const int t = threadIdx.x, lane = t & 63, wave = t >> 6;
    const int wm = wave >> 2, wn = wave & 3;
    const int fr = lane & 15, fg = lane >> 4;

    const int srowL = wave * 8 + (lane >> 3);
    const int scol  = 8 * ((lane & 7) ^ (lane >> 3));
    const f16* ga = A  + (long)(m0 + srowL) * 4096 + scol;
    const f16* gb = Bt + (long)(n0 + srowL) * 4096 + scol;
    const int woff = wave * 1024;

    auto ST = [&](int sel, int c, int row0, int kt) {
        const f16* g = sel ? gb : ga;
        async_ld16(g + (long)row0 * 4096 + kt * 64,
                   L + c * 65536 + sel * 32768 + row0 * 128 + woff);
    };

    ST(0, 0, 0, 0);   ST(0, 0, 64, 0);  ST(0, 0, 128, 0); ST(0, 0, 192, 0);
    ST(1, 0, 0, 0);   ST(1, 0, 64, 0);  ST(1, 0, 128, 0); ST(1, 0, 192, 0);
    ST(1, 1, 0, 1);   ST(1, 1, 64, 1);  ST(1, 1, 128, 1); ST(1, 1, 192, 1);
    ST(0, 1, 0, 1);   ST(0, 1, 128, 1);
    asm volatile("s_waitcnt vmcnt(6)" ::: "memory");
    __builtin_amdgcn_s_barrier();

    const int abase = wm * 128;
    const int bbase = wn * 64;

    for (int tt = 0; tt < 64; ++tt) {
        const int c = tt & 1;
        const char* bufA = L + c * 65536;
        const char* bufB = bufA + 32768;
        f16x8 bf[2][4];

#pragma unroll
        for (int q = 0; q < 4; ++q) {
            if (q == 0) {
#pragma unroll
                for (int ks = 0; ks < 2; ++ks)
#pragma unroll
                    for (int nf = 0; nf < 4; ++nf) {
                        int r = bbase + nf * 16 + fr;
                        bf[ks][nf] = *(const f16x8*)(bufB + r * 128 +
                                        ((ks * 64 + 16 * fg) ^ ((r & 7) << 4)));
                    }
            }
            f16x8 af[2][2];
#pragma unroll
            for (int ks = 0; ks < 2; ++ks)
#pragma unroll
                for (int i = 0; i < 2; ++i) {
                    int r = abase + (2 * q + i) * 16 + fr;
                    af[ks][i] = *(const f16x8*)(bufA + r * 128 +
                                    ((ks * 64 + 16 * fg) ^ ((r & 7) << 4)));
                }
            if (q == 0) { if (tt + 1 < 64) { ST(0, c ^ 1,  64, tt + 1);
                                             ST(0, c ^ 1, 192, tt + 1); } }
            if (q == 1) { if (tt + 2 < 64) { ST(1, c,   0, tt + 2);
                                             ST(1, c,  64, tt + 2); } }
            if (q == 2) { if (tt + 2 < 64) { ST(1, c, 128, tt + 2);
                                             ST(1, c, 192, tt + 2); } }
            if (q == 3) { if (tt + 2 < 64) { ST(0, c,   0, tt + 2);
                                             ST(0, c, 128, tt + 2); } }
            __builtin_amdgcn_s_barrier();
            __builtin_amdgcn_s_setprio(1);
#pragma unroll
            for (int ks = 0; ks < 2; ++ks)
#pragma unroll
                for (int i = 0; i < 2; ++i)
#pragma unroll
                    for (int nf = 0; nf < 4; ++nf)
                        acc[2 * q + i][nf] = __builtin_amdgcn_mfma_f32_16x16x32_f16(
                            af[ks][i], bf[ks][nf], acc[2 * q + i][nf], 0, 0, 0);
            __builtin_amdgcn_s_setprio(0);
            if (q == 3) {
                if (tt < 62)       asm volatile("s_waitcnt vmcnt(6)" ::: "memory");
                else if (tt == 62) asm volatile("s_waitcnt vmcnt(0)" ::: "memory");
            }
            __builtin_amdgcn_s_barrier();
        }
    }
}

// GEMM1: hidden @ Wqkv^T -> q (RoPE+scale fused), k (RoPE fused), V^T (fused).
// 256x384 tiles -> 256 blocks = 1 full dispatch round.
__global__ __launch_bounds__(512) void k_gemm_qkv(
    const f16* __restrict__ A, const f16* __restrict__ Bt,
    f16* __restrict__ q, f16* __restrict__ kk_, f16* __restrict__ vt,
    const float* __restrict__ cosb, const float* __restrict__ sinb) {
    __shared__ __align__(16) char L[163840];       // full 160KB pool
    const int bid = blockIdx.x;                    // 256 = 16m x 16n
    const int swzb = (bid & 7) * 32 + (bid >> 3);  // XCD-bijective
    const int m0 = (swzb >> 4) * 256, n0 = (swzb & 15) * 384;
    f32x4 acc[8][6] = {};
    gemm384_core(A, Bt, L, m0, n0, acc);

    const int lane = threadIdx.x & 63, wave = threadIdx.x >> 6;
    const int wm = wave >> 2, wn = wave & 3;
    const int fr = lane & 15, fg = lane >> 4;
#pragma unroll
    for (int mf = 0; mf < 8; ++mf) {
        int r0 = m0 + wm * 128 + mf * 16 + 4 * fg;
        int b = r0 >> 11, s = r0 & (Sn - 1);   // r0 multiple of 4: same b, s..s+3
        const float* cb_ = cosb + ((long)b * Sn + s) * 64;
        const float* sb_ = sinb + ((long)b * Sn + s) * 64;
#pragma unroll
        for (int nf = 0; nf < 6; ++nf) {
            int cc = n0 + wn * 96 + nf * 16 + fr;
            int d = cc & 127;
            if (cc < 5120) {
                float vals[4];
#pragma unroll
                for (int e = 0; e < 4; ++e) vals[e] = acc[mf][nf][e];
                if (d < 64) {
                    int ci = d >> 1;
                    bool odd = (d & 1);
#pragma unroll
                    for (int e = 0; e < 4; ++e) {
                        float p = __shfl_xor(vals[e], 1, 64);   // lane^1 = d^1
                        float c = cb_[e * 64 + ci], sv = sb_[e * 64 + ci];
                        vals[e] = odd ? (vals[e] * c + p * sv)
                                      : (vals[e] * c - p * sv);
                    }
                }
                if (cc < 4096) {
                    int h = cc >> 7;
#pragma unroll
                    for (int e = 0; e < 4; ++e)
                        q[(((long)b * NH + h) * Sn + s + e) * HD + d] =
                            (f16)(vals[e] * QSC);
                } else {
                    int h = (cc - 4096) >> 7;
#pragma unroll
                    for (int e = 0; e < 4; ++e)
                        kk_[(((long)b * NKV + h) * Sn + s + e) * HD + d] =
                            (f16)vals[e];
                }
            } else {
                int h = (cc - 5120) >> 7;
                uint2 w = {pk2(acc[mf][nf][0], acc[mf][nf][1]),
                           pk2(acc[mf][nf][2], acc[mf][nf][3])};
                *(uint2*)&vt[(((long)b * NKV + h) * HD + d) * Sn + s] = w;
            }
        }
    }
}

// GEMM2: attn_out @ wo^T -> d_out f32, 256 blocks (16x16) = 1 full round
__global__ __launch_bounds__(512) void k_gemm_out(
    const f16* __restrict__ A, const f16* __restrict__ Bt,
    float* __restrict__ out) {
    __shared__ __align__(16) char L[131072];
    const int bid = blockIdx.x;
    const int swzb = (bid & 7) * 32 + (bid >> 3);
    const int m0 = (swzb >> 4) * 256, n0 = (swzb & 15) * 256;
    f32x4 acc[8][4] = {};
    gemm256_core(A, Bt, L, m0, n0, acc);

    const int lane = threadIdx.x & 63, wave = threadIdx.x >> 6;
    const int wm = wave >> 2, wn = wave & 3;
    const int fr = lane & 15, fg = lane >> 4;
#pragma unroll
    for (int mf = 0; mf < 8; ++mf) {
        int r0 = m0 + wm * 128 + mf * 16 + 4 * fg;
#pragma unroll
        for (int nf = 0; nf < 4; ++nf) {
            int cc = n0 + wn * 64 + nf * 16 + fr;
#pragma unroll
            for (int e = 0; e < 4; ++e)
                out[(long)(r0 + e) * 4096 + cc] = acc[mf][nf][e];
        }
    }
}

// ---------------------------------------------------------------------------
// Flash attention v6 (r13-proven): QBLK=256 (8 waves x 32 q), 32x32x16 MFMA,
// in-register P via pk2 + shfl_xor(32); swapped QK^T (q lane-local softmax).
//   A: row=lane&31, k=8*(lane>>5)+e   B: k=8*(lane>>5)+e, col=lane&31
//   C: col=lane&31, row=(reg&3)+8*(reg>>2)+4*(lane>>5)

__device__ __forceinline__ f16x8 ld_sw256(const f16* base, int r, int c) {
    int byte = r * 256 + ((c * 2) ^ ((r & 7) << 4));
    return *(const f16x8*)((const char*)base + byte);
}
__device__ __forceinline__ f16x8 ld_sw128(const f16* base, int r, int c) {
    int byte = r * 128 + ((c * 2) ^ ((r & 7) << 4));
    return *(const f16x8*)((const char*)base + byte);
}

// K tile [64 kv][128 d] f16 = 16KB = 16 chunks; 8 waves x 2 chunks
__device__ __forceinline__ void stage_k(const f16* __restrict__ Kb, f16* ksm,
                                        int k0, int wave, int lane) {
#pragma unroll
    for (int i = 0; i < 2; ++i) {
        int dbase = (i * 8 + wave) * 1024;
        int d = dbase + lane * 16;
        int row = d >> 8;
        int cb = (d & 255) ^ ((row & 7) << 4);
        async_ld16(Kb + (long)(k0 + row) * HD + (cb >> 1), (char*)ksm + dbase);
    }
}
__device__ __forceinline__ void stage_v(const f16* __restrict__ Vb, f16* vsm,
                                        int k0, int wave, int lane) {
#pragma unroll
    for (int i = 0; i < 2; ++i) {
        int dbase = (i * 8 + wave) * 1024;
        int d = dbase + lane * 16;
        int row = d >> 7;
        int cb = (d & 127) ^ ((row & 7) << 4);
        async_ld16(Vb + (long)row * Sn + k0 + (cb >> 1), (char*)vsm + dbase);
    }
}

__global__ __launch_bounds__(512) void k_attn(
    const f16* __restrict__ Q, const f16* __restrict__ K,
    const f16* __restrict__ Vt, f16* __restrict__ O) {
    __shared__ __align__(16) f16 Ksm[2][64 * 128];   // 32KB
    __shared__ __align__(16) f16 Vsm[2][128 * 64];   // 32KB

    // grid 512: id = ((b*4 + hg)*8 + pos)*8 + kvh; pos pairs (heavy, light)
    const int id = blockIdx.x;
    const int kvh = id & 7;                 // XCD-local KV
    const int r_ = id >> 3;
    const int pos = r_ & 7;
    const int qt = (pos & 1) ? (pos >> 1) : (7 - (pos >> 1)); // 7,0,6,1,5,2,4,3
    const int hg = (r_ >> 3) & 3;
    const int b  = r_ >> 5;
    const int h  = kvh * 4 + hg;
    const int q0 = qt * 256;
    const int t = threadIdx.x, lane = t & 63, wave = t >> 6;
    const int q0w = q0 + wave * 32;
    const int lq = lane & 31, hi = lane >> 5;

    const f16* Qb = Q + ((long)(b * NH + h) * Sn) * HD;
    const f16* Kb = K + ((long)(b * NKV + kvh) * Sn) * HD;
    const f16* Vb = Vt + ((long)(b * NKV + kvh) * HD) * Sn;

    f16x8 qf[8];
#pragma unroll
    for (int s = 0; s < 8; ++s)
        qf[s] = *(const f16x8*)&Qb[(long)(q0w + lq) * HD + 16 * s + 8 * hi];

    f32x16 oacc[4] = {};
    float mrun = -1e30f, lrun = 0.f;

    const int nt = q0 / 64 + 4;   // cover q0+255
    stage_k(Kb, Ksm[0], 0, wave, lane);
    stage_v(Vb, Vsm[0], 0, wave, lane);

    for (int kt = 0; kt < nt; ++kt) {
        const int k0 = kt * 64;
        const int cur = kt & 1;
        if (kt + 1 < nt) {
            stage_k(Kb, Ksm[cur ^ 1], (kt + 1) * 64, wave, lane);
            stage_v(Vb, Vsm[cur ^ 1], (kt + 1) * 64, wave, lane);
            asm volatile("s_waitcnt vmcnt(4)" ::: "memory"); // cur tile landed
        } else {
            asm volatile("s_waitcnt vmcnt(0)" ::: "memory");
        }
        __builtin_amdgcn_s_barrier();

        if (k0 <= q0w + 31) {
            f32x16 st[2] = {};
#pragma unroll
            for (int s = 0; s < 8; ++s) {
                f16x8 kf0 = ld_sw256(Ksm[cur], lq,      16 * s + 8 * hi);
                f16x8 kf1 = ld_sw256(Ksm[cur], 32 + lq, 16 * s + 8 * hi);
                st[0] = __builtin_amdgcn_mfma_f32_32x32x16_f16(kf0, qf[s], st[0], 0, 0, 0);
                st[1] = __builtin_amdgcn_mfma_f32_32x32x16_f16(kf1, qf[s], st[1], 0, 0, 0);
            }
            const bool full = (k0 + 63 <= q0w);
            if (!full) {
#pragma unroll
                for (int mt = 0; mt < 2; ++mt)
#pragma unroll
                    for (int r = 0; r < 16; ++r) {
                        int kvv = k0 + 32 * mt + (r & 3) + 8 * (r >> 2) + 4 * hi;
                        if (kvv > q0w + lq) st[mt][r] = -1e30f;
                    }
            }
            float pm = st[0][0];
#pragma unroll
            for (int r = 1; r < 16; ++r) pm = fmaxf(pm, st[0][r]);
#pragma unroll
            for (int r = 0; r < 16; ++r) pm = fmaxf(pm, st[1][r]);
            pm = fmaxf(pm, __shfl_xor(pm, 32, 64));
            if (__any(pm > mrun + 8.f)) {
                float mn = fmaxf(mrun, pm);
                float sc = fexp2(mrun - mn);
                mrun = mn;
                lrun *= sc;
                float scr[16];
#pragma unroll
                for (int r = 0; r < 16; ++r)
                    scr[r] = __shfl(sc, (r & 3) + 8 * (r >> 2) + 4 * hi, 64);
#pragma unroll
                for (int db = 0; db < 4; ++db)
#pragma unroll
                    for (int r = 0; r < 16; ++r)
                        oacc[db][r] *= scr[r];
            }
            unsigned pw[2][8];
#pragma unroll
            for (int mt = 0; mt < 2; ++mt)
#pragma unroll
                for (int i = 0; i < 8; ++i) {
                    float p0 = fexp2(st[mt][2 * i]     - mrun);
                    float p1 = fexp2(st[mt][2 * i + 1] - mrun);
                    lrun += p0 + p1;
                    pw[mt][i] = pk2(p0, p1);
                }
#pragma unroll
            for (int s = 0; s < 4; ++s) {
                const int mt = s >> 1, sl = s & 1;
                unsigned a0 = pw[mt][4 * sl], a1 = pw[mt][4 * sl + 1];
                unsigned a2 = pw[mt][4 * sl + 2], a3 = pw[mt][4 * sl + 3];
                unsigned own0 = hi ? a2 : a0, own1 = hi ? a3 : a1;
                unsigned snd0 = hi ? a0 : a2, snd1 = hi ? a1 : a3;
                unsigned rx0 = (unsigned)__shfl_xor((int)snd0, 32, 64);
                unsigned rx1 = (unsigned)__shfl_xor((int)snd1, 32, 64);
                union { unsigned u[4]; f16x8 v; } pu;
                pu.u[0] = hi ? rx0 : own0;
                pu.u[1] = hi ? rx1 : own1;
                pu.u[2] = hi ? own0 : rx0;
                pu.u[3] = hi ? own1 : rx1;
#pragma unroll
                for (int db = 0; db < 4; ++db) {
                    f16x8 vf = ld_sw128(Vsm[cur], 32 * db + lq, 16 * s + 8 * hi);
                    oacc[db] = __builtin_amdgcn_mfma_f32_32x32x16_f16(pu.v, vf, oacc[db], 0, 0, 0);
                }
            }
        }
        __builtin_amdgcn_s_barrier();
    }

    lrun += __shfl_xor(lrun, 32, 64);
    float li = 1.f / lrun;
    float ir[16];
#pragma unroll
    for (int r = 0; r < 16; ++r)
        ir[r] = __shfl(li, (r & 3) + 8 * (r >> 2) + 4 * hi, 64);
#pragma unroll
    for (int db = 0; db < 4; ++db)
#pragma unroll
        for (int r = 0; r < 16; ++r) {
            int qloc = (r & 3) + 8 * (r >> 2) + 4 * hi;
            long tok = (long)b * Sn + q0w + qloc;
            O[tok * (NH * HD) + h * HD + 32 * db + lq] = (f16)(oacc[db][r] * ir[r]);
        }
}

// sentinel if workspace too small
__global__ void k_ws_fail(float* out) { out[0] = 1.0e9f; }

// ---------------------------------------------------------------------------
extern "C" void kernel_launch(void* const* d_in, const int* in_sizes, int n_in,
                              void* d_out, int out_size, void* d_ws, size_t ws_size,
                              hipStream_t stream) {
    const float* hs   = (const float*)d_in[0];
    const float* wq   = (const float*)d_in[1];
    const float* wk   = (const float*)d_in[2];
    const float* wv   = (const float*)d_in[3];
    const float* wo   = (const float*)d_in[4];
    const float* cosb = (const float*)d_in[5];
    const float* sinb = (const float*)d_in[6];
    float* out = (float*)d_out;

    const size_t OFF_WQKV = 0;
    const size_t OFF_WO   = 50331648;
    const size_t OFF_HID  = 83886080;
    const size_t OFF_Q    = 117440512;
    const size_t OFF_K    = 150994944;
    const size_t OFF_VT   = 167772160;
    const size_t WS_NEED  = 176160768;
    if (ws_size < WS_NEED) { k_ws_fail<<<1, 1, 0, stream>>>(out); return; }

    char* ws = (char*)d_ws;
    f16* wqkv_t = (f16*)(ws + OFF_WQKV);
    f16* wo_t   = (f16*)(ws + OFF_WO);
    f16* hid    = (f16*)(ws + OFF_HID);
    f16* qb     = (f16*)(ws + OFF_Q);
    f16* kb     = (f16*)(ws + OFF_K);
    f16* vtb    = (f16*)(ws + OFF_VT);

    // 1 prep dispatch: 8192 cvt blocks + (4096+1024+1024+4096) tcvt blocks
    k_prep<<<dim3(18432), 256, 0, stream>>>(hs, hid, wq, wk, wv, wo, wqkv_t, wo_t);
    k_gemm_qkv<<<dim3(256), 512, 0, stream>>>(hid, wqkv_t, qb, kb, vtb, cosb, sinb);
    k_attn<<<dim3(512), 512, 0, stream>>>(qb, kb, vtb, hid);
    k_gemm_out<<<dim3(256), 512, 0, stream>>>(hid, wo_t, out);
}